// Round 16
// baseline (559.846 us; speedup 1.0000x reference)
//
#include <hip/hip_runtime.h>
#include <cstdint>
#include <cstddef>

#define DD 64
#define TILE 64    // k_tile_linear row tile
#define LSTR 65    // padded f32 LDS row stride (k_tile_linear)
#define ESTR 72    // bf16 LDS row stride (u16 units): 144B rows, 16B-aligned frags
#define NREP 64    // stat-replica count: spreads block atomics over 64*128 floats
constexpr float BN_EPS  = 1e-5f;
constexpr float DEG_EPS = 1e-6f;

typedef __attribute__((ext_vector_type(8))) short bf16x8;
typedef __attribute__((ext_vector_type(4))) float f32x4;
typedef __attribute__((ext_vector_type(4))) unsigned int u32x4;

__device__ __forceinline__ float fatomic_add(float* p, float v) {
    return unsafeAtomicAdd(p, v);   // hardware global_atomic_add_f32
}

__device__ __forceinline__ uint32_t bf16r(float x) {   // round-to-nearest-even bf16
    uint32_t u = __float_as_uint(x);
    return (u + 0x7fffu + ((u >> 16) & 1u)) >> 16;
}
__device__ __forceinline__ uint32_t pack2(float lo, float hi) {
    return (bf16r(hi) << 16) | bf16r(lo);
}
__device__ __forceinline__ float bfl(uint32_t u) { return __uint_as_float(u << 16); }
__device__ __forceinline__ float bfh(uint32_t u) { return __uint_as_float(u & 0xffff0000u); }

// =============== tiled linear + fused edge-degree count ======================
// y==0 (A1h): fp32 output + CSR degree counting. y>=1: bf16 output.
__global__ __launch_bounds__(256) void k_tile_linear(
    const float* __restrict__ x, int R,
    const float* __restrict__ w0, const float* __restrict__ b0, float* __restrict__ o0,
    const float* __restrict__ w1, const float* __restrict__ b1, float* __restrict__ o1,
    const float* __restrict__ w2, const float* __restrict__ b2, float* __restrict__ o2,
    const float* __restrict__ w3, const float* __restrict__ b3, float* __restrict__ o3,
    const float* __restrict__ w4, const float* __restrict__ b4, float* __restrict__ o4,
    const int* __restrict__ src, const int* __restrict__ dst,
    int* __restrict__ cnt2, int N, int E)
{
    const float* w; const float* b; float* o;
    switch (blockIdx.y) {
        case 0:  w = w0; b = b0; o = o0; break;
        case 1:  w = w1; b = b1; o = o1; break;
        case 2:  w = w2; b = b2; o = o2; break;
        case 3:  w = w3; b = b3; o = o3; break;
        default: w = w4; b = b4; o = o4; break;
    }
    __shared__ float ldsE[TILE * LSTR];
    int tid  = threadIdx.x;
    int lane = tid & 63;
    int base = blockIdx.x * TILE;
    int rem  = R - base; if (rem > TILE) rem = TILE;
    int qu   = __builtin_amdgcn_readfirstlane(tid >> 6);   // wave id 0..3, SGPR

    const float4* x4 = reinterpret_cast<const float4*>(x + (size_t)base * DD);
    #pragma unroll
    for (int j = 0; j < 4; ++j) {
        int f4 = j * 256 + tid;          // float4 index in tile
        int r  = f4 >> 4, c = f4 & 15;
        if (r < rem) {
            float4 v = x4[f4];
            ldsE[r * LSTR + c * 4 + 0] = v.x;
            ldsE[r * LSTR + c * 4 + 1] = v.y;
            ldsE[r * LSTR + c * 4 + 2] = v.z;
            ldsE[r * LSTR + c * 4 + 3] = v.w;
        }
    }
    __syncthreads();

    float acc[16];
    #pragma unroll
    for (int i = 0; i < 16; ++i) acc[i] = b[qu * 16 + i];
    #pragma unroll 4
    for (int k = 0; k < 64; ++k) {
        float ev = ldsE[lane * LSTR + k];
        const float* wq = w + (size_t)(qu * 16) * DD + k;
        #pragma unroll
        for (int i = 0; i < 16; ++i)
            acc[i] = fmaf(ev, wq[(size_t)i * DD], acc[i]);
    }
    __syncthreads();   // all reads of ldsE done -> safe to overwrite
    #pragma unroll
    for (int i = 0; i < 16; ++i)
        ldsE[lane * LSTR + qu * 16 + i] = acc[i];
    __syncthreads();

    if (blockIdx.y == 0) {
        // fp32 write-out
        float4* outp4 = reinterpret_cast<float4*>(o + (size_t)base * DD);
        #pragma unroll
        for (int j = 0; j < 4; ++j) {
            int f4 = j * 256 + tid;
            int r  = f4 >> 4, c = f4 & 15;
            if (r < rem) {
                float4 v;
                v.x = ldsE[r * LSTR + c * 4 + 0];
                v.y = ldsE[r * LSTR + c * 4 + 1];
                v.z = ldsE[r * LSTR + c * 4 + 2];
                v.w = ldsE[r * LSTR + c * 4 + 3];
                outp4[f4] = v;
            }
        }
        // fused CSR degree count (independent work, hides under stores)
        int stride = gridDim.x * 256;
        for (int ee = blockIdx.x * 256 + tid; ee < E; ee += stride) {
            atomicAdd(&cnt2[dst[ee]], 1);        // fwd counts at [0,N)
            atomicAdd(&cnt2[N + src[ee]], 1);    // bwd counts at [N,2N)
        }
    } else {
        // bf16 write-out: [R][64] u16 rows (128B), uint2 = 4 bf16 per store
        uint2* ob2 = reinterpret_cast<uint2*>(o);
        #pragma unroll
        for (int j = 0; j < 4; ++j) {
            int f = j * 256 + tid;       // [0,1024): 64 rows x 16 uint2
            int r = f >> 4, q = f & 15;
            if (r < rem) {
                uint2 v;
                v.x = pack2(ldsE[r * LSTR + 4 * q + 0], ldsE[r * LSTR + 4 * q + 1]);
                v.y = pack2(ldsE[r * LSTR + 4 * q + 2], ldsE[r * LSTR + 4 * q + 3]);
                ob2[(size_t)(base + r) * 16 + q] = v;
            }
        }
    }
}

// =============== fused edge gate (MFMA, 64-edge tiles, bf16 B-tables) ========
__global__ __launch_bounds__(256) void k_edge_fused(
    const float* __restrict__ e,
    const int* __restrict__ src, const int* __restrict__ dst,
    const uint16_t* __restrict__ B1b, const uint16_t* __restrict__ B2b,
    const float* __restrict__ w, const float* __restrict__ b,
    uint32_t* __restrict__ packed, float4* ecopy, float* __restrict__ sums, int E)
{
    __shared__ __align__(16) uint16_t ldsEb[TILE * ESTR];  // bf16 e   (9216 B)
    __shared__ __align__(16) uint16_t ldsBG[TILE * ESTR];  // bf16 B3 -> bf16 g0
    __shared__ float red[256];
    uint32_t* eb32 = reinterpret_cast<uint32_t*>(ldsEb);
    int tid  = threadIdx.x;
    int lane = tid & 63;
    int base = blockIdx.x * TILE;
    int rem  = E - base; if (rem > TILE) rem = TILE;
    int qu   = __builtin_amdgcn_readfirstlane(tid >> 6);

    // phase 0a: read e tile into regs
    const float4* e4 = reinterpret_cast<const float4*>(e + (size_t)base * DD);
    float4 ev[4];
    #pragma unroll
    for (int j = 0; j < 4; ++j) {
        int f4 = j * 256 + tid;
        int r  = f4 >> 4;
        ev[j] = (r < rem) ? e4[f4] : float4{0.f, 0.f, 0.f, 0.f};
    }

    // phase 0b: issue this wave's 32 bf16 B-row loads (128B/row; latency hides
    // under staging + MFMA)
    float b1r[16], b2r[16];
    #pragma unroll
    for (int it = 0; it < 16; ++it) {
        int el = qu * 16 + it;               // wave-uniform
        if (el < rem) {
            int ee = base + el;
            int s = src[ee], t = dst[ee];    // scalar loads (uniform address)
            b1r[it] = bfl((uint32_t)B1b[(size_t)s * DD + lane]);
            b2r[it] = bfl((uint32_t)B2b[(size_t)t * DD + lane]);
        } else { b1r[it] = 0.f; b2r[it] = 0.f; }
    }

    // phase 1: bf16 e -> ldsEb, bf16 B3 -> ldsBG, fp32 e passthrough
    #pragma unroll
    for (int j = 0; j < 4; ++j) {
        int f4 = j * 256 + tid;
        int r  = f4 >> 4, c = f4 & 15;
        if (r < rem) {
            eb32[r * (ESTR / 2) + 2 * c + 0] = pack2(ev[j].x, ev[j].y);
            eb32[r * (ESTR / 2) + 2 * c + 1] = pack2(ev[j].z, ev[j].w);
            if (ecopy) ecopy[(size_t)base * 16 + f4] = ev[j];
        }
    }
    #pragma unroll
    for (int i = 0; i < 16; ++i) {
        int idx = i * 256 + tid;             // 0..4095, coalesced (L2-hot 16KB)
        int r = idx >> 6, c = idx & 63;
        ldsBG[r * ESTR + c] = (uint16_t)bf16r(w[idx]);
    }
    __syncthreads();

    // phase 2: MFMA  g0[16qu..16qu+16) x d[0..64) = e-slice @ B3^T
    int kg   = lane >> 4;
    int lrow = lane & 15;
    f32x4 acc[4] = {{0,0,0,0},{0,0,0,0},{0,0,0,0},{0,0,0,0}};
    bf16x8 a0 = __builtin_bit_cast(bf16x8,
        *(const u32x4*)&ldsEb[(qu * 16 + lrow) * ESTR + kg * 8]);        // k 0..31
    bf16x8 a1 = __builtin_bit_cast(bf16x8,
        *(const u32x4*)&ldsEb[(qu * 16 + lrow) * ESTR + 32 + kg * 8]);   // k 32..63
    #pragma unroll
    for (int t = 0; t < 4; ++t) {
        bf16x8 bb0 = __builtin_bit_cast(bf16x8,
            *(const u32x4*)&ldsBG[(t * 16 + lrow) * ESTR + kg * 8]);
        bf16x8 bb1 = __builtin_bit_cast(bf16x8,
            *(const u32x4*)&ldsBG[(t * 16 + lrow) * ESTR + 32 + kg * 8]);
        acc[t] = __builtin_amdgcn_mfma_f32_16x16x32_bf16(a0, bb0, acc[t], 0, 0, 0);
        acc[t] = __builtin_amdgcn_mfma_f32_16x16x32_bf16(a1, bb1, acc[t], 0, 0, 0);
    }
    __syncthreads();   // all waves done reading B3 -> ldsBG reusable for g0

    // D store (m89-verified C/D map: col = lane&15, row = (lane>>4)*4 + reg)
    #pragma unroll
    for (int t = 0; t < 4; ++t) {
        float bias = b[t * 16 + lrow];
        #pragma unroll
        for (int r = 0; r < 4; ++r) {
            ldsBG[(qu * 16 + kg * 4 + r) * ESTR + t * 16 + lrow] =
                (uint16_t)bf16r(acc[t][r] + bias);
        }
    }
    __syncthreads();

    // phase 3: v = g0 + B1row + B2row, stats, packed bf16 (g,e) write
    float ps = 0.f, pq = 0.f;
    #pragma unroll
    for (int it = 0; it < 16; ++it) {
        int el = qu * 16 + it;
        if (el < rem) {
            int ee = base + el;
            uint32_t ebits = ldsEb[el * ESTR + lane];
            uint32_t gbits = ldsBG[el * ESTR + lane];
            float gv = __uint_as_float(gbits << 16);
            float v  = gv + b1r[it] + b2r[it];
            packed[(size_t)ee * DD + lane] = (ebits << 16) | bf16r(v);
            ps += v; pq += v * v;
        }
    }
    float* srep = sums + (size_t)(blockIdx.x & (NREP - 1)) * 128;
    red[tid] = ps; __syncthreads();
    if (tid < 64) fatomic_add(&srep[tid],      red[tid] + red[tid+64] + red[tid+128] + red[tid+192]);
    __syncthreads();
    red[tid] = pq; __syncthreads();
    if (tid < 64) fatomic_add(&srep[64 + tid], red[tid] + red[tid+64] + red[tid+128] + red[tid+192]);
}

// ---------------- fold replicated stats into scale/shift ---------------------
__global__ void k_bn_final(const float* __restrict__ reps, float inv_cnt,
                           const float* __restrict__ gamma, const float* __restrict__ beta,
                           float* __restrict__ scale, float* __restrict__ shift)
{
    int d = threadIdx.x;
    if (d >= DD) return;
    float s = 0.f, q = 0.f;
    #pragma unroll 8
    for (int r = 0; r < NREP; ++r) {
        s += reps[r * 128 + d];
        q += reps[r * 128 + 64 + d];
    }
    float mean = s * inv_cnt;
    float var  = fmaxf(q * inv_cnt - mean * mean, 0.f);
    float rs   = rsqrtf(var + BN_EPS);
    float sc   = gamma[d] * rs;
    scale[d] = sc;
    shift[d] = beta[d] - mean * sc;
}

// hierarchical exclusive scan: block-local -> add (carry computed inline)
__global__ __launch_bounds__(1024) void k_scan_blk(
    const int* __restrict__ cnt, int* __restrict__ row, int* __restrict__ part, int n)
{
    __shared__ int tmp[1024];
    int tid = threadIdx.x;
    int i   = blockIdx.x * 1024 + tid;
    int v   = (i < n) ? cnt[i] : 0;
    tmp[tid] = v; __syncthreads();
    for (int off = 1; off < 1024; off <<= 1) {
        int t = (tid >= off) ? tmp[tid - off] : 0;
        __syncthreads();
        tmp[tid] += t;
        __syncthreads();
    }
    if (i < n) row[i] = tmp[tid] - v;            // local exclusive
    if (tid == 1023) part[blockIdx.x] = tmp[1023];  // raw block total
}

__global__ __launch_bounds__(1024) void k_scan_add(
    int* __restrict__ row, int* __restrict__ cur, const int* __restrict__ part,
    int n, int total)
{
    int carry = 0;
    for (int j = 0; j < (int)blockIdx.x; ++j) carry += part[j];  // uniform s_loads
    int i = blockIdx.x * 1024 + threadIdx.x;
    if (i < n) {
        int r = row[i] + carry;
        row[i] = r; cur[i] = r;
    }
    if (i == 0) row[n] = total;
}

// place packed (eid, other-node) pairs (standalone: random scatter overlaps
// within itself; fusing it into edge_fused cost +99us -- round 15 lesson)
__global__ __launch_bounds__(256) void k_place(
    const int* __restrict__ src, const int* __restrict__ dst,
    int* __restrict__ cur2, int2* __restrict__ pair2, int N, int E)
{
    int ee = blockIdx.x * 256 + threadIdx.x;
    if (ee >= E) return;
    int s = src[ee], t = dst[ee];
    int pf = atomicAdd(&cur2[t], 1);
    pair2[pf] = make_int2(ee, s);
    int pb = atomicAdd(&cur2[N + s], 1);
    pair2[pb] = make_int2(ee, t);        // bwd slots live at [E, 2E)
}

// ---------------- merged gather, 16 edges in flight, bf16 Ah -----------------
__global__ __launch_bounds__(256) void k_gather2(
    const uint32_t* __restrict__ packed,
    const int2* __restrict__ pair2, const int* __restrict__ row2,
    const uint16_t* __restrict__ A2b, const uint16_t* __restrict__ A3b,
    const float* __restrict__ e_scale, const float* __restrict__ e_shift,
    float* __restrict__ agg_f, float* __restrict__ agg_b, int N)
{
    int gw = (blockIdx.x * 256 + threadIdx.x) >> 6;
    if (gw >= 2 * N) return;
    int lane = threadIdx.x & 63;
    bool bwd = gw >= N;
    int wid  = bwd ? gw - N : gw;
    const uint2* Ah2 = reinterpret_cast<const uint2*>(bwd ? A3b : A2b);
    float* agg       = bwd ? agg_b : agg_f;
    int beg = row2[gw], end = row2[gw + 1];   // fwd rows [0,N), bwd rows [N,2N)
    int q  = lane >> 4;      // edge slot 0..3
    int dj = lane & 15;      // float4 column slot
    float4 sc = reinterpret_cast<const float4*>(e_scale)[dj];
    float4 sh = reinterpret_cast<const float4*>(e_shift)[dj];
    float4 num = {0.f, 0.f, 0.f, 0.f};
    float4 den = {0.f, 0.f, 0.f, 0.f};
    const uint4* p4 = reinterpret_cast<const uint4*>(packed);
    for (int k = beg + q; k < end; k += 16) {
        bool h1 = k + 4 < end, h2 = k + 8 < end, h3 = k + 12 < end;
        int2 p0 = pair2[k];
        int2 p1 = h1 ? pair2[k + 4]  : p0;
        int2 p2 = h2 ? pair2[k + 8]  : p0;
        int2 p3 = h3 ? pair2[k + 12] : p0;
        uint4 w0 = p4[(size_t)p0.x * 16 + dj];
        uint4 w1 = p4[(size_t)p1.x * 16 + dj];
        uint4 w2 = p4[(size_t)p2.x * 16 + dj];
        uint4 w3 = p4[(size_t)p3.x * 16 + dj];
        uint2 a0 = Ah2[(size_t)p0.y * 16 + dj];
        uint2 a1 = Ah2[(size_t)p1.y * 16 + dj];
        uint2 a2 = Ah2[(size_t)p2.y * 16 + dj];
        uint2 a3 = Ah2[(size_t)p3.y * 16 + dj];
        float m1 = h1 ? 1.f : 0.f, m2 = h2 ? 1.f : 0.f, m3 = h3 ? 1.f : 0.f;
        #define ACC_PAIR(wv, av, m)                                              \
        {                                                                        \
            float s0 = 1.f / (1.f + __expf(-(fmaxf(bfl(wv.x) * sc.x + sh.x, 0.f) + bfh(wv.x)))); \
            float s1 = 1.f / (1.f + __expf(-(fmaxf(bfl(wv.y) * sc.y + sh.y, 0.f) + bfh(wv.y)))); \
            float s2 = 1.f / (1.f + __expf(-(fmaxf(bfl(wv.z) * sc.z + sh.z, 0.f) + bfh(wv.z)))); \
            float s3 = 1.f / (1.f + __expf(-(fmaxf(bfl(wv.w) * sc.w + sh.w, 0.f) + bfh(wv.w)))); \
            s0 *= m; s1 *= m; s2 *= m; s3 *= m;                                  \
            num.x = fmaf(s0, bfl(av.x), num.x);                                  \
            num.y = fmaf(s1, bfh(av.x), num.y);                                  \
            num.z = fmaf(s2, bfl(av.y), num.z);                                  \
            num.w = fmaf(s3, bfh(av.y), num.w);                                  \
            den.x += s0; den.y += s1; den.z += s2; den.w += s3;                  \
        }
        ACC_PAIR(w0, a0, 1.f)
        ACC_PAIR(w1, a1, m1)
        ACC_PAIR(w2, a2, m2)
        ACC_PAIR(w3, a3, m3)
        #undef ACC_PAIR
    }
    #pragma unroll
    for (int off = 16; off <= 32; off <<= 1) {
        num.x += __shfl_xor(num.x, off); num.y += __shfl_xor(num.y, off);
        num.z += __shfl_xor(num.z, off); num.w += __shfl_xor(num.w, off);
        den.x += __shfl_xor(den.x, off); den.y += __shfl_xor(den.y, off);
        den.z += __shfl_xor(den.z, off); den.w += __shfl_xor(den.w, off);
    }
    if (q == 0) {
        float4 res;
        res.x = num.x / (den.x + DEG_EPS);
        res.y = num.y / (den.y + DEG_EPS);
        res.z = num.z / (den.z + DEG_EPS);
        res.w = num.w / (den.w + DEG_EPS);
        reinterpret_cast<float4*>(agg)[(size_t)wid * 16 + dj] = res;
    }
}

// ---------------- h_pre = A1h + agg_f + agg_b, + replicated column stats -----
__global__ __launch_bounds__(256) void k_node_pre(
    const float* __restrict__ A1h,
    const float* __restrict__ agg_f, const float* __restrict__ agg_b,
    float* __restrict__ hpre, float* __restrict__ sums, long long total)
{
    int tid = threadIdx.x;
    long long idx = (long long)blockIdx.x * 256 + tid;
    long long stride = (long long)gridDim.x * 256;
    float ps = 0.f, pq = 0.f;
    for (; idx < total; idx += stride) {
        float v = A1h[idx] + agg_f[idx] + agg_b[idx];
        hpre[idx] = v;
        ps += v; pq += v * v;
    }
    float* srep = sums + (size_t)(blockIdx.x & (NREP - 1)) * 128;
    __shared__ float red[256];
    red[tid] = ps; __syncthreads();
    if (tid < 64) fatomic_add(&srep[tid],      red[tid] + red[tid+64] + red[tid+128] + red[tid+192]);
    __syncthreads();
    red[tid] = pq; __syncthreads();
    if (tid < 64) fatomic_add(&srep[64 + tid], red[tid] + red[tid+64] + red[tid+128] + red[tid+192]);
}

// ---------------- finish h: BN affine + relu + residual (in place) -----------
__global__ __launch_bounds__(256) void k_node_out(
    const float* __restrict__ h,
    const float* __restrict__ scale, const float* __restrict__ shift,
    float* __restrict__ out, long long total)
{
    long long idx = (long long)blockIdx.x * 256 + threadIdx.x;
    long long stride = (long long)gridDim.x * 256;
    for (; idx < total; idx += stride) {
        int d = (int)(idx & (DD - 1));
        float v = out[idx] * scale[d] + shift[d];
        out[idx] = fmaxf(v, 0.f) + h[idx];
    }
}

extern "C" void kernel_launch(void* const* d_in, const int* in_sizes, int n_in,
                              void* d_out, int out_size, void* d_ws, size_t ws_size,
                              hipStream_t stream)
{
    const float* h    = (const float*)d_in[0];
    const float* e    = (const float*)d_in[1];
    const int*   src  = (const int*)d_in[2];
    const int*   dst  = (const int*)d_in[3];
    const float* A1w  = (const float*)d_in[4];
    const float* A1b  = (const float*)d_in[5];
    const float* A2w  = (const float*)d_in[6];
    const float* A2b  = (const float*)d_in[7];
    const float* A3w  = (const float*)d_in[8];
    const float* A3b  = (const float*)d_in[9];
    const float* B1w  = (const float*)d_in[10];
    const float* B1b  = (const float*)d_in[11];
    const float* B2w  = (const float*)d_in[12];
    const float* B2b  = (const float*)d_in[13];
    const float* B3w  = (const float*)d_in[14];
    const float* B3b  = (const float*)d_in[15];
    const float* bnhg = (const float*)d_in[16];
    const float* bnhb = (const float*)d_in[17];
    const float* bneg = (const float*)d_in[18];
    const float* bneb = (const float*)d_in[19];

    const int N = in_sizes[0] / DD;
    const int E = in_sizes[1] / DD;
    const size_t ND = (size_t)N * DD;
    const size_t ED = (size_t)E * DD;

    float* ws    = (float*)d_ws;
    float* A1h   = ws + 0 * ND;
    float* A2h   = ws + 1 * ND;   // bf16 content
    float* A3h   = ws + 2 * ND;   // bf16 content
    float* B1h   = ws + 3 * ND;   // bf16 content
    float* B2h   = ws + 4 * ND;   // bf16 content
    float* agg_f = ws + 5 * ND;
    float* agg_b = ws + 6 * ND;
    float* stats = ws + 7 * ND;
    const size_t STATS_F = 16640;
    float* e_rep   = stats;
    float* h_rep   = stats + 8192;
    float* e_scale = stats + 16384;
    float* e_shift = stats + 16448;
    float* h_scale = stats + 16512;
    float* h_shift = stats + 16576;

    const int nscan   = 2 * N;
    const int nb_scan = (nscan + 1023) / 1024;
    const size_t int_count = (size_t)(4 * N + 1 + nb_scan) + 4 * (size_t)E + 2;
    const size_t need_big  = (7 * ND + STATS_F + ED) * sizeof(float) + int_count * sizeof(int);
    const bool   ws_big    = ws_size >= need_big;

    uint32_t* pk_ws = (uint32_t*)(stats + STATS_F);     // ED uint32 (only if ws_big)
    int*      ibase = (int*)(ws_big ? (float*)(pk_ws + ED) : (stats + STATS_F));
    int*  cur2   = ibase;                     // 2N (counts -> cursors)
    int*  row2   = ibase + 2 * N;             // 2N+1
    int*  part   = ibase + 4 * N + 1;         // nb_scan (raw block sums)
    int2* pair2  = (int2*)(((uintptr_t)(part + nb_scan) + 7) & ~(uintptr_t)7); // 2E pairs

    float* out  = (float*)d_out;
    float* gbuf = out + ND;   // out e-region

    hipMemsetAsync(stats, 0, STATS_F * sizeof(float), stream);
    hipMemsetAsync(cur2, 0, 2 * (size_t)N * sizeof(int), stream);

    dim3 blk(256);
    int nt_n  = (N + TILE - 1) / TILE;
    int nt_e  = (E + TILE - 1) / TILE;
    int nb_e  = (E + 255) / 256;

    // node linears + fused degree count
    k_tile_linear<<<dim3(nt_n, 5), blk, 0, stream>>>(h, N,
        A1w, A1b, A1h,  A2w, A2b, A2h,  A3w, A3b, A3h,
        B1w, B1b, B1h,  B2w, B2b, B2h,
        src, dst, cur2, N, E);

    // CSR scan (carry folded into scan_add) + place
    k_scan_blk<<<nb_scan, 1024, 0, stream>>>(cur2, row2, part, nscan);
    k_scan_add<<<nb_scan, 1024, 0, stream>>>(row2, cur2, part, nscan, 2 * E);
    k_place<<<nb_e, blk, 0, stream>>>(src, dst, cur2, pair2, N, E);

    // fused edge gate + BN-e stats + packed (g,e) + e passthrough
    uint32_t* pkmem = ws_big ? pk_ws : (uint32_t*)gbuf;
    k_edge_fused<<<nt_e, blk, 0, stream>>>(e, src, dst,
                                           (const uint16_t*)B1h, (const uint16_t*)B2h,
                                           B3w, B3b,
                                           pkmem, ws_big ? (float4*)gbuf : nullptr,
                                           e_rep, E);
    k_bn_final<<<1, 64, 0, stream>>>(e_rep, 1.0f / (float)E, bneg, bneb,
                                     e_scale, e_shift);

    // merged gather with inline sigma recompute from packed rows
    int nb_g2 = (int)(((size_t)2 * N * 64 + 255) / 256);
    k_gather2<<<nb_g2, blk, 0, stream>>>(pkmem, pair2, row2,
                                         (const uint16_t*)A2h, (const uint16_t*)A3h,
                                         e_scale, e_shift, agg_f, agg_b, N);

    k_node_pre<<<1024, blk, 0, stream>>>(A1h, agg_f, agg_b,
        out, h_rep, (long long)ND);
    k_bn_final<<<1, 64, 0, stream>>>(h_rep, 1.0f / (float)N, bnhg, bnhb,
                                     h_scale, h_shift);
    k_node_out<<<1024, blk, 0, stream>>>(h, h_scale, h_shift,
                                         out, (long long)ND);

    if (!ws_big) {
        hipMemcpyAsync(gbuf, e, ED * sizeof(float), hipMemcpyDeviceToDevice, stream);
    }
}

// Round 17
// 485.225 us; speedup vs baseline: 1.1538x; 1.1538x over previous
//
#include <hip/hip_runtime.h>
#include <cstdint>
#include <cstddef>

#define DD 64
#define TILE 64    // k_tile_linear row tile / k_edge_fused edge tile
#define LSTR 65    // padded f32 LDS row stride (k_tile_linear)
#define ESTR 72    // bf16 LDS row stride (u16 units): 144B rows, 16B-aligned frags
#define NREP 64    // stat-replica count: spreads block atomics over 64*128 floats
constexpr float BN_EPS  = 1e-5f;
constexpr float DEG_EPS = 1e-6f;

typedef __attribute__((ext_vector_type(8))) short bf16x8;
typedef __attribute__((ext_vector_type(4))) float f32x4;
typedef __attribute__((ext_vector_type(4))) unsigned int u32x4;

__device__ __forceinline__ float fatomic_add(float* p, float v) {
    return unsafeAtomicAdd(p, v);   // hardware global_atomic_add_f32
}

__device__ __forceinline__ uint32_t bf16r(float x) {   // round-to-nearest-even bf16
    uint32_t u = __float_as_uint(x);
    return (u + 0x7fffu + ((u >> 16) & 1u)) >> 16;
}
__device__ __forceinline__ uint32_t pack2(float lo, float hi) {
    return (bf16r(hi) << 16) | bf16r(lo);
}
__device__ __forceinline__ float bfl(uint32_t u) { return __uint_as_float(u << 16); }
__device__ __forceinline__ float bfh(uint32_t u) { return __uint_as_float(u & 0xffff0000u); }

// =============== tiled linear + fused edge-degree count ======================
// y==0 (A1h): fp32 output + CSR degree counting. y>=1: bf16 output.
__global__ __launch_bounds__(256) void k_tile_linear(
    const float* __restrict__ x, int R,
    const float* __restrict__ w0, const float* __restrict__ b0, float* __restrict__ o0,
    const float* __restrict__ w1, const float* __restrict__ b1, float* __restrict__ o1,
    const float* __restrict__ w2, const float* __restrict__ b2, float* __restrict__ o2,
    const float* __restrict__ w3, const float* __restrict__ b3, float* __restrict__ o3,
    const float* __restrict__ w4, const float* __restrict__ b4, float* __restrict__ o4,
    const int* __restrict__ src, const int* __restrict__ dst,
    int* __restrict__ cnt2, int N, int E)
{
    const float* w; const float* b; float* o;
    switch (blockIdx.y) {
        case 0:  w = w0; b = b0; o = o0; break;
        case 1:  w = w1; b = b1; o = o1; break;
        case 2:  w = w2; b = b2; o = o2; break;
        case 3:  w = w3; b = b3; o = o3; break;
        default: w = w4; b = b4; o = o4; break;
    }
    __shared__ float ldsE[TILE * LSTR];
    int tid  = threadIdx.x;
    int lane = tid & 63;
    int base = blockIdx.x * TILE;
    int rem  = R - base; if (rem > TILE) rem = TILE;
    int qu   = __builtin_amdgcn_readfirstlane(tid >> 6);   // wave id 0..3, SGPR

    const float4* x4 = reinterpret_cast<const float4*>(x + (size_t)base * DD);
    #pragma unroll
    for (int j = 0; j < 4; ++j) {
        int f4 = j * 256 + tid;          // float4 index in tile
        int r  = f4 >> 4, c = f4 & 15;
        if (r < rem) {
            float4 v = x4[f4];
            ldsE[r * LSTR + c * 4 + 0] = v.x;
            ldsE[r * LSTR + c * 4 + 1] = v.y;
            ldsE[r * LSTR + c * 4 + 2] = v.z;
            ldsE[r * LSTR + c * 4 + 3] = v.w;
        }
    }
    __syncthreads();

    float acc[16];
    #pragma unroll
    for (int i = 0; i < 16; ++i) acc[i] = b[qu * 16 + i];
    #pragma unroll 4
    for (int k = 0; k < 64; ++k) {
        float ev = ldsE[lane * LSTR + k];
        const float* wq = w + (size_t)(qu * 16) * DD + k;
        #pragma unroll
        for (int i = 0; i < 16; ++i)
            acc[i] = fmaf(ev, wq[(size_t)i * DD], acc[i]);
    }
    __syncthreads();   // all reads of ldsE done -> safe to overwrite
    #pragma unroll
    for (int i = 0; i < 16; ++i)
        ldsE[lane * LSTR + qu * 16 + i] = acc[i];
    __syncthreads();

    if (blockIdx.y == 0) {
        // fp32 write-out
        float4* outp4 = reinterpret_cast<float4*>(o + (size_t)base * DD);
        #pragma unroll
        for (int j = 0; j < 4; ++j) {
            int f4 = j * 256 + tid;
            int r  = f4 >> 4, c = f4 & 15;
            if (r < rem) {
                float4 v;
                v.x = ldsE[r * LSTR + c * 4 + 0];
                v.y = ldsE[r * LSTR + c * 4 + 1];
                v.z = ldsE[r * LSTR + c * 4 + 2];
                v.w = ldsE[r * LSTR + c * 4 + 3];
                outp4[f4] = v;
            }
        }
        // fused CSR degree count (independent work, hides under stores)
        int stride = gridDim.x * 256;
        for (int ee = blockIdx.x * 256 + tid; ee < E; ee += stride) {
            atomicAdd(&cnt2[dst[ee]], 1);        // fwd counts at [0,N)
            atomicAdd(&cnt2[N + src[ee]], 1);    // bwd counts at [N,2N)
        }
    } else {
        // bf16 write-out: [R][64] u16 rows (128B), uint2 = 4 bf16 per store
        uint2* ob2 = reinterpret_cast<uint2*>(o);
        #pragma unroll
        for (int j = 0; j < 4; ++j) {
            int f = j * 256 + tid;       // [0,1024): 64 rows x 16 uint2
            int r = f >> 4, q = f & 15;
            if (r < rem) {
                uint2 v;
                v.x = pack2(ldsE[r * LSTR + 4 * q + 0], ldsE[r * LSTR + 4 * q + 1]);
                v.y = pack2(ldsE[r * LSTR + 4 * q + 2], ldsE[r * LSTR + 4 * q + 3]);
                ob2[(size_t)(base + r) * 16 + q] = v;
            }
        }
    }
}

// =============== fused edge gate (MFMA, 64-edge tiles, tile-local place) =====
// Each block also places ITS OWN 64 edges into the CSR pair arrays: src/dst
// are L1-hot, work is perfectly balanced, and the scatter latency retires
// under staging + MFMA. (Round-15's blockIdx*512 mapping was imbalanced/cold;
// standalone k_place cost ~127us exposed -- round-16 lesson.)
__global__ __launch_bounds__(256) void k_edge_fused(
    const float* __restrict__ e,
    const int* __restrict__ src, const int* __restrict__ dst,
    const uint16_t* __restrict__ B1b, const uint16_t* __restrict__ B2b,
    const float* __restrict__ w, const float* __restrict__ b,
    uint32_t* __restrict__ packed, float4* ecopy, float* __restrict__ sums,
    int* __restrict__ cur2, int2* __restrict__ pair2, int N, int E)
{
    __shared__ __align__(16) uint16_t ldsEb[TILE * ESTR];  // bf16 e   (9216 B)
    __shared__ __align__(16) uint16_t ldsBG[TILE * ESTR];  // bf16 B3 -> bf16 g0
    __shared__ float red[256];
    uint32_t* eb32 = reinterpret_cast<uint32_t*>(ldsEb);
    int tid  = threadIdx.x;
    int lane = tid & 63;
    int base = blockIdx.x * TILE;
    int rem  = E - base; if (rem > TILE) rem = TILE;
    int qu   = __builtin_amdgcn_readfirstlane(tid >> 6);

    // phase 0a: read e tile into regs
    const float4* e4 = reinterpret_cast<const float4*>(e + (size_t)base * DD);
    float4 ev[4];
    #pragma unroll
    for (int j = 0; j < 4; ++j) {
        int f4 = j * 256 + tid;
        int r  = f4 >> 4;
        ev[j] = (r < rem) ? e4[f4] : float4{0.f, 0.f, 0.f, 0.f};
    }

    // phase 0b: issue this wave's 32 bf16 B-row loads (latency hides under MFMA)
    float b1r[16], b2r[16];
    #pragma unroll
    for (int it = 0; it < 16; ++it) {
        int el = qu * 16 + it;               // wave-uniform
        if (el < rem) {
            int ee = base + el;
            int s = src[ee], t = dst[ee];    // scalar loads (uniform address)
            b1r[it] = bfl((uint32_t)B1b[(size_t)s * DD + lane]);
            b2r[it] = bfl((uint32_t)B2b[(size_t)t * DD + lane]);
        } else { b1r[it] = 0.f; b2r[it] = 0.f; }
    }

    // phase 0c: tile-local CSR place (threads 0..rem-1; src/dst L1-hot)
    if (tid < rem) {
        int ee = base + tid;
        int s = src[ee], t = dst[ee];
        int pf = atomicAdd(&cur2[t], 1);
        pair2[pf] = make_int2(ee, s);
        int pb = atomicAdd(&cur2[N + s], 1);
        pair2[pb] = make_int2(ee, t);        // bwd slots live at [E, 2E)
    }

    // phase 1: bf16 e -> ldsEb, bf16 B3 -> ldsBG, fp32 e passthrough
    #pragma unroll
    for (int j = 0; j < 4; ++j) {
        int f4 = j * 256 + tid;
        int r  = f4 >> 4, c = f4 & 15;
        if (r < rem) {
            eb32[r * (ESTR / 2) + 2 * c + 0] = pack2(ev[j].x, ev[j].y);
            eb32[r * (ESTR / 2) + 2 * c + 1] = pack2(ev[j].z, ev[j].w);
            if (ecopy) ecopy[(size_t)base * 16 + f4] = ev[j];
        }
    }
    #pragma unroll
    for (int i = 0; i < 16; ++i) {
        int idx = i * 256 + tid;             // 0..4095, coalesced (L2-hot 16KB)
        int r = idx >> 6, c = idx & 63;
        ldsBG[r * ESTR + c] = (uint16_t)bf16r(w[idx]);
    }
    __syncthreads();

    // phase 2: MFMA  g0[16qu..16qu+16) x d[0..64) = e-slice @ B3^T
    int kg   = lane >> 4;
    int lrow = lane & 15;
    f32x4 acc[4] = {{0,0,0,0},{0,0,0,0},{0,0,0,0},{0,0,0,0}};
    bf16x8 a0 = __builtin_bit_cast(bf16x8,
        *(const u32x4*)&ldsEb[(qu * 16 + lrow) * ESTR + kg * 8]);        // k 0..31
    bf16x8 a1 = __builtin_bit_cast(bf16x8,
        *(const u32x4*)&ldsEb[(qu * 16 + lrow) * ESTR + 32 + kg * 8]);   // k 32..63
    #pragma unroll
    for (int t = 0; t < 4; ++t) {
        bf16x8 bb0 = __builtin_bit_cast(bf16x8,
            *(const u32x4*)&ldsBG[(t * 16 + lrow) * ESTR + kg * 8]);
        bf16x8 bb1 = __builtin_bit_cast(bf16x8,
            *(const u32x4*)&ldsBG[(t * 16 + lrow) * ESTR + 32 + kg * 8]);
        acc[t] = __builtin_amdgcn_mfma_f32_16x16x32_bf16(a0, bb0, acc[t], 0, 0, 0);
        acc[t] = __builtin_amdgcn_mfma_f32_16x16x32_bf16(a1, bb1, acc[t], 0, 0, 0);
    }
    __syncthreads();   // all waves done reading B3 -> ldsBG reusable for g0

    // D store (m89-verified C/D map: col = lane&15, row = (lane>>4)*4 + reg)
    #pragma unroll
    for (int t = 0; t < 4; ++t) {
        float bias = b[t * 16 + lrow];
        #pragma unroll
        for (int r = 0; r < 4; ++r) {
            ldsBG[(qu * 16 + kg * 4 + r) * ESTR + t * 16 + lrow] =
                (uint16_t)bf16r(acc[t][r] + bias);
        }
    }
    __syncthreads();

    // phase 3: v = g0 + B1row + B2row, stats, packed bf16 (g,e) write
    float ps = 0.f, pq = 0.f;
    #pragma unroll
    for (int it = 0; it < 16; ++it) {
        int el = qu * 16 + it;
        if (el < rem) {
            int ee = base + el;
            uint32_t ebits = ldsEb[el * ESTR + lane];
            uint32_t gbits = ldsBG[el * ESTR + lane];
            float gv = __uint_as_float(gbits << 16);
            float v  = gv + b1r[it] + b2r[it];
            packed[(size_t)ee * DD + lane] = (ebits << 16) | bf16r(v);
            ps += v; pq += v * v;
        }
    }
    float* srep = sums + (size_t)(blockIdx.x & (NREP - 1)) * 128;
    red[tid] = ps; __syncthreads();
    if (tid < 64) fatomic_add(&srep[tid],      red[tid] + red[tid+64] + red[tid+128] + red[tid+192]);
    __syncthreads();
    red[tid] = pq; __syncthreads();
    if (tid < 64) fatomic_add(&srep[64 + tid], red[tid] + red[tid+64] + red[tid+128] + red[tid+192]);
}

// ---------------- fold replicated stats into scale/shift ---------------------
__global__ void k_bn_final(const float* __restrict__ reps, float inv_cnt,
                           const float* __restrict__ gamma, const float* __restrict__ beta,
                           float* __restrict__ scale, float* __restrict__ shift)
{
    int d = threadIdx.x;
    if (d >= DD) return;
    float s = 0.f, q = 0.f;
    #pragma unroll 8
    for (int r = 0; r < NREP; ++r) {
        s += reps[r * 128 + d];
        q += reps[r * 128 + 64 + d];
    }
    float mean = s * inv_cnt;
    float var  = fmaxf(q * inv_cnt - mean * mean, 0.f);
    float rs   = rsqrtf(var + BN_EPS);
    float sc   = gamma[d] * rs;
    scale[d] = sc;
    shift[d] = beta[d] - mean * sc;
}

// hierarchical exclusive scan: block-local -> add (carry computed inline)
__global__ __launch_bounds__(1024) void k_scan_blk(
    const int* __restrict__ cnt, int* __restrict__ row, int* __restrict__ part, int n)
{
    __shared__ int tmp[1024];
    int tid = threadIdx.x;
    int i   = blockIdx.x * 1024 + tid;
    int v   = (i < n) ? cnt[i] : 0;
    tmp[tid] = v; __syncthreads();
    for (int off = 1; off < 1024; off <<= 1) {
        int t = (tid >= off) ? tmp[tid - off] : 0;
        __syncthreads();
        tmp[tid] += t;
        __syncthreads();
    }
    if (i < n) row[i] = tmp[tid] - v;            // local exclusive
    if (tid == 1023) part[blockIdx.x] = tmp[1023];  // raw block total
}

__global__ __launch_bounds__(1024) void k_scan_add(
    int* __restrict__ row, int* __restrict__ cur, const int* __restrict__ part,
    int n, int total)
{
    int carry = 0;
    for (int j = 0; j < (int)blockIdx.x; ++j) carry += part[j];  // uniform s_loads
    int i = blockIdx.x * 1024 + threadIdx.x;
    if (i < n) {
        int r = row[i] + carry;
        row[i] = r; cur[i] = r;
    }
    if (i == 0) row[n] = total;
}

// ---------------- merged gather, 16 edges in flight, bf16 Ah -----------------
__global__ __launch_bounds__(256) void k_gather2(
    const uint32_t* __restrict__ packed,
    const int2* __restrict__ pair2, const int* __restrict__ row2,
    const uint16_t* __restrict__ A2b, const uint16_t* __restrict__ A3b,
    const float* __restrict__ e_scale, const float* __restrict__ e_shift,
    float* __restrict__ agg_f, float* __restrict__ agg_b, int N)
{
    int gw = (blockIdx.x * 256 + threadIdx.x) >> 6;
    if (gw >= 2 * N) return;
    int lane = threadIdx.x & 63;
    bool bwd = gw >= N;
    int wid  = bwd ? gw - N : gw;
    const uint2* Ah2 = reinterpret_cast<const uint2*>(bwd ? A3b : A2b);
    float* agg       = bwd ? agg_b : agg_f;
    int beg = row2[gw], end = row2[gw + 1];   // fwd rows [0,N), bwd rows [N,2N)
    int q  = lane >> 4;      // edge slot 0..3
    int dj = lane & 15;      // float4 column slot
    float4 sc = reinterpret_cast<const float4*>(e_scale)[dj];
    float4 sh = reinterpret_cast<const float4*>(e_shift)[dj];
    float4 num = {0.f, 0.f, 0.f, 0.f};
    float4 den = {0.f, 0.f, 0.f, 0.f};
    const uint4* p4 = reinterpret_cast<const uint4*>(packed);
    for (int k = beg + q; k < end; k += 16) {
        bool h1 = k + 4 < end, h2 = k + 8 < end, h3 = k + 12 < end;
        int2 p0 = pair2[k];
        int2 p1 = h1 ? pair2[k + 4]  : p0;
        int2 p2 = h2 ? pair2[k + 8]  : p0;
        int2 p3 = h3 ? pair2[k + 12] : p0;
        uint4 w0 = p4[(size_t)p0.x * 16 + dj];
        uint4 w1 = p4[(size_t)p1.x * 16 + dj];
        uint4 w2 = p4[(size_t)p2.x * 16 + dj];
        uint4 w3 = p4[(size_t)p3.x * 16 + dj];
        uint2 a0 = Ah2[(size_t)p0.y * 16 + dj];
        uint2 a1 = Ah2[(size_t)p1.y * 16 + dj];
        uint2 a2 = Ah2[(size_t)p2.y * 16 + dj];
        uint2 a3 = Ah2[(size_t)p3.y * 16 + dj];
        float m1 = h1 ? 1.f : 0.f, m2 = h2 ? 1.f : 0.f, m3 = h3 ? 1.f : 0.f;
        #define ACC_PAIR(wv, av, m)                                              \
        {                                                                        \
            float s0 = 1.f / (1.f + __expf(-(fmaxf(bfl(wv.x) * sc.x + sh.x, 0.f) + bfh(wv.x)))); \
            float s1 = 1.f / (1.f + __expf(-(fmaxf(bfl(wv.y) * sc.y + sh.y, 0.f) + bfh(wv.y)))); \
            float s2 = 1.f / (1.f + __expf(-(fmaxf(bfl(wv.z) * sc.z + sh.z, 0.f) + bfh(wv.z)))); \
            float s3 = 1.f / (1.f + __expf(-(fmaxf(bfl(wv.w) * sc.w + sh.w, 0.f) + bfh(wv.w)))); \
            s0 *= m; s1 *= m; s2 *= m; s3 *= m;                                  \
            num.x = fmaf(s0, bfl(av.x), num.x);                                  \
            num.y = fmaf(s1, bfh(av.x), num.y);                                  \
            num.z = fmaf(s2, bfl(av.y), num.z);                                  \
            num.w = fmaf(s3, bfh(av.y), num.w);                                  \
            den.x += s0; den.y += s1; den.z += s2; den.w += s3;                  \
        }
        ACC_PAIR(w0, a0, 1.f)
        ACC_PAIR(w1, a1, m1)
        ACC_PAIR(w2, a2, m2)
        ACC_PAIR(w3, a3, m3)
        #undef ACC_PAIR
    }
    #pragma unroll
    for (int off = 16; off <= 32; off <<= 1) {
        num.x += __shfl_xor(num.x, off); num.y += __shfl_xor(num.y, off);
        num.z += __shfl_xor(num.z, off); num.w += __shfl_xor(num.w, off);
        den.x += __shfl_xor(den.x, off); den.y += __shfl_xor(den.y, off);
        den.z += __shfl_xor(den.z, off); den.w += __shfl_xor(den.w, off);
    }
    if (q == 0) {
        float4 res;
        res.x = num.x / (den.x + DEG_EPS);
        res.y = num.y / (den.y + DEG_EPS);
        res.z = num.z / (den.z + DEG_EPS);
        res.w = num.w / (den.w + DEG_EPS);
        reinterpret_cast<float4*>(agg)[(size_t)wid * 16 + dj] = res;
    }
}

// ---------------- h_pre = A1h + agg_f + agg_b, + replicated column stats -----
__global__ __launch_bounds__(256) void k_node_pre(
    const float* __restrict__ A1h,
    const float* __restrict__ agg_f, const float* __restrict__ agg_b,
    float* __restrict__ hpre, float* __restrict__ sums, long long total)
{
    int tid = threadIdx.x;
    long long idx = (long long)blockIdx.x * 256 + tid;
    long long stride = (long long)gridDim.x * 256;
    float ps = 0.f, pq = 0.f;
    for (; idx < total; idx += stride) {
        float v = A1h[idx] + agg_f[idx] + agg_b[idx];
        hpre[idx] = v;
        ps += v; pq += v * v;
    }
    float* srep = sums + (size_t)(blockIdx.x & (NREP - 1)) * 128;
    __shared__ float red[256];
    red[tid] = ps; __syncthreads();
    if (tid < 64) fatomic_add(&srep[tid],      red[tid] + red[tid+64] + red[tid+128] + red[tid+192]);
    __syncthreads();
    red[tid] = pq; __syncthreads();
    if (tid < 64) fatomic_add(&srep[64 + tid], red[tid] + red[tid+64] + red[tid+128] + red[tid+192]);
}

// ---------------- finish h: BN affine + relu + residual (in place) -----------
__global__ __launch_bounds__(256) void k_node_out(
    const float* __restrict__ h,
    const float* __restrict__ scale, const float* __restrict__ shift,
    float* __restrict__ out, long long total)
{
    long long idx = (long long)blockIdx.x * 256 + threadIdx.x;
    long long stride = (long long)gridDim.x * 256;
    for (; idx < total; idx += stride) {
        int d = (int)(idx & (DD - 1));
        float v = out[idx] * scale[d] + shift[d];
        out[idx] = fmaxf(v, 0.f) + h[idx];
    }
}

extern "C" void kernel_launch(void* const* d_in, const int* in_sizes, int n_in,
                              void* d_out, int out_size, void* d_ws, size_t ws_size,
                              hipStream_t stream)
{
    const float* h    = (const float*)d_in[0];
    const float* e    = (const float*)d_in[1];
    const int*   src  = (const int*)d_in[2];
    const int*   dst  = (const int*)d_in[3];
    const float* A1w  = (const float*)d_in[4];
    const float* A1b  = (const float*)d_in[5];
    const float* A2w  = (const float*)d_in[6];
    const float* A2b  = (const float*)d_in[7];
    const float* A3w  = (const float*)d_in[8];
    const float* A3b  = (const float*)d_in[9];
    const float* B1w  = (const float*)d_in[10];
    const float* B1b  = (const float*)d_in[11];
    const float* B2w  = (const float*)d_in[12];
    const float* B2b  = (const float*)d_in[13];
    const float* B3w  = (const float*)d_in[14];
    const float* B3b  = (const float*)d_in[15];
    const float* bnhg = (const float*)d_in[16];
    const float* bnhb = (const float*)d_in[17];
    const float* bneg = (const float*)d_in[18];
    const float* bneb = (const float*)d_in[19];

    const int N = in_sizes[0] / DD;
    const int E = in_sizes[1] / DD;
    const size_t ND = (size_t)N * DD;
    const size_t ED = (size_t)E * DD;

    float* ws    = (float*)d_ws;
    float* A1h   = ws + 0 * ND;
    float* A2h   = ws + 1 * ND;   // bf16 content
    float* A3h   = ws + 2 * ND;   // bf16 content
    float* B1h   = ws + 3 * ND;   // bf16 content
    float* B2h   = ws + 4 * ND;   // bf16 content
    float* agg_f = ws + 5 * ND;
    float* agg_b = ws + 6 * ND;
    float* stats = ws + 7 * ND;
    const size_t STATS_F = 16640;
    float* e_rep   = stats;
    float* h_rep   = stats + 8192;
    float* e_scale = stats + 16384;
    float* e_shift = stats + 16448;
    float* h_scale = stats + 16512;
    float* h_shift = stats + 16576;

    const int nscan   = 2 * N;
    const int nb_scan = (nscan + 1023) / 1024;
    const size_t int_count = (size_t)(4 * N + 1 + nb_scan) + 4 * (size_t)E + 2;
    const size_t need_big  = (7 * ND + STATS_F + ED) * sizeof(float) + int_count * sizeof(int);
    const bool   ws_big    = ws_size >= need_big;

    uint32_t* pk_ws = (uint32_t*)(stats + STATS_F);     // ED uint32 (only if ws_big)
    int*      ibase = (int*)(ws_big ? (float*)(pk_ws + ED) : (stats + STATS_F));
    int*  cur2   = ibase;                     // 2N (counts -> cursors)
    int*  row2   = ibase + 2 * N;             // 2N+1
    int*  part   = ibase + 4 * N + 1;         // nb_scan (raw block sums)
    int2* pair2  = (int2*)(((uintptr_t)(part + nb_scan) + 7) & ~(uintptr_t)7); // 2E pairs

    float* out  = (float*)d_out;
    float* gbuf = out + ND;   // out e-region

    hipMemsetAsync(stats, 0, STATS_F * sizeof(float), stream);
    hipMemsetAsync(cur2, 0, 2 * (size_t)N * sizeof(int), stream);

    dim3 blk(256);
    int nt_n  = (N + TILE - 1) / TILE;
    int nt_e  = (E + TILE - 1) / TILE;

    // node linears + fused degree count
    k_tile_linear<<<dim3(nt_n, 5), blk, 0, stream>>>(h, N,
        A1w, A1b, A1h,  A2w, A2b, A2h,  A3w, A3b, A3h,
        B1w, B1b, B1h,  B2w, B2b, B2h,
        src, dst, cur2, N, E);

    // CSR scan (carry folded into scan_add); place fused into edge_fused
    k_scan_blk<<<nb_scan, 1024, 0, stream>>>(cur2, row2, part, nscan);
    k_scan_add<<<nb_scan, 1024, 0, stream>>>(row2, cur2, part, nscan, 2 * E);

    // fused edge gate + BN-e stats + packed (g,e) + e passthrough + tile place
    uint32_t* pkmem = ws_big ? pk_ws : (uint32_t*)gbuf;
    k_edge_fused<<<nt_e, blk, 0, stream>>>(e, src, dst,
                                           (const uint16_t*)B1h, (const uint16_t*)B2h,
                                           B3w, B3b,
                                           pkmem, ws_big ? (float4*)gbuf : nullptr,
                                           e_rep, cur2, pair2, N, E);
    k_bn_final<<<1, 64, 0, stream>>>(e_rep, 1.0f / (float)E, bneg, bneb,
                                     e_scale, e_shift);

    // merged gather with inline sigma recompute from packed rows
    int nb_g2 = (int)(((size_t)2 * N * 64 + 255) / 256);
    k_gather2<<<nb_g2, blk, 0, stream>>>(pkmem, pair2, row2,
                                         (const uint16_t*)A2h, (const uint16_t*)A3h,
                                         e_scale, e_shift, agg_f, agg_b, N);

    k_node_pre<<<1024, blk, 0, stream>>>(A1h, agg_f, agg_b,
        out, h_rep, (long long)ND);
    k_bn_final<<<1, 64, 0, stream>>>(h_rep, 1.0f / (float)N, bnhg, bnhb,
                                     h_scale, h_shift);
    k_node_out<<<1024, blk, 0, stream>>>(h, h_scale, h_shift,
                                         out, (long long)ND);

    if (!ws_big) {
        hipMemcpyAsync(gbuf, e, ED * sizeof(float), hipMemcpyDeviceToDevice, stream);
    }
}

// Round 18
// 482.656 us; speedup vs baseline: 1.1599x; 1.0053x over previous
//
#include <hip/hip_runtime.h>
#include <cstdint>
#include <cstddef>

#define DD 64
#define TILE 64    // row/edge tile
#define LSTR 65    // padded f32 LDS row stride (k_tile_linear)
#define ESTR 72    // bf16 LDS row stride (u16 units): 144B rows, 16B-aligned frags
#define NREP 64    // stat-replica count: spreads block atomics over 64*128 floats
constexpr float BN_EPS  = 1e-5f;
constexpr float DEG_EPS = 1e-6f;

typedef __attribute__((ext_vector_type(8))) short bf16x8;
typedef __attribute__((ext_vector_type(4))) float f32x4;
typedef __attribute__((ext_vector_type(4))) unsigned int u32x4;

__device__ __forceinline__ float fatomic_add(float* p, float v) {
    return unsafeAtomicAdd(p, v);   // hardware global_atomic_add_f32
}

__device__ __forceinline__ uint32_t bf16r(float x) {   // round-to-nearest-even bf16
    uint32_t u = __float_as_uint(x);
    return (u + 0x7fffu + ((u >> 16) & 1u)) >> 16;
}
__device__ __forceinline__ uint32_t pack2(float lo, float hi) {
    return (bf16r(hi) << 16) | bf16r(lo);
}
__device__ __forceinline__ float bfl(uint32_t u) { return __uint_as_float(u << 16); }
__device__ __forceinline__ float bfh(uint32_t u) { return __uint_as_float(u & 0xffff0000u); }

// =============== A1 linear (fp32, VALU) + fused edge-degree count ============
__global__ __launch_bounds__(256) void k_tile_linear1(
    const float* __restrict__ x, int R,
    const float* __restrict__ w, const float* __restrict__ b, float* __restrict__ o,
    const int* __restrict__ src, const int* __restrict__ dst,
    int* __restrict__ cnt2, int N, int E)
{
    __shared__ float ldsE[TILE * LSTR];
    int tid  = threadIdx.x;
    int lane = tid & 63;
    int base = blockIdx.x * TILE;
    int rem  = R - base; if (rem > TILE) rem = TILE;
    int qu   = __builtin_amdgcn_readfirstlane(tid >> 6);   // wave id 0..3, SGPR

    const float4* x4 = reinterpret_cast<const float4*>(x + (size_t)base * DD);
    #pragma unroll
    for (int j = 0; j < 4; ++j) {
        int f4 = j * 256 + tid;
        int r  = f4 >> 4, c = f4 & 15;
        if (r < rem) {
            float4 v = x4[f4];
            ldsE[r * LSTR + c * 4 + 0] = v.x;
            ldsE[r * LSTR + c * 4 + 1] = v.y;
            ldsE[r * LSTR + c * 4 + 2] = v.z;
            ldsE[r * LSTR + c * 4 + 3] = v.w;
        }
    }
    __syncthreads();

    float acc[16];
    #pragma unroll
    for (int i = 0; i < 16; ++i) acc[i] = b[qu * 16 + i];
    #pragma unroll 4
    for (int k = 0; k < 64; ++k) {
        float ev = ldsE[lane * LSTR + k];
        const float* wq = w + (size_t)(qu * 16) * DD + k;
        #pragma unroll
        for (int i = 0; i < 16; ++i)
            acc[i] = fmaf(ev, wq[(size_t)i * DD], acc[i]);
    }
    __syncthreads();
    #pragma unroll
    for (int i = 0; i < 16; ++i)
        ldsE[lane * LSTR + qu * 16 + i] = acc[i];
    __syncthreads();

    float4* outp4 = reinterpret_cast<float4*>(o + (size_t)base * DD);
    #pragma unroll
    for (int j = 0; j < 4; ++j) {
        int f4 = j * 256 + tid;
        int r  = f4 >> 4, c = f4 & 15;
        if (r < rem) {
            float4 v;
            v.x = ldsE[r * LSTR + c * 4 + 0];
            v.y = ldsE[r * LSTR + c * 4 + 1];
            v.z = ldsE[r * LSTR + c * 4 + 2];
            v.w = ldsE[r * LSTR + c * 4 + 3];
            outp4[f4] = v;
        }
    }
    // fused CSR degree count (independent work, hides under stores)
    int stride = gridDim.x * 256;
    for (int ee = blockIdx.x * 256 + tid; ee < E; ee += stride) {
        atomicAdd(&cnt2[dst[ee]], 1);        // fwd counts at [0,N)
        atomicAdd(&cnt2[N + src[ee]], 1);    // bwd counts at [N,2N)
    }
}

// =============== 4 bf16 node linears on the MATRIX pipe ======================
// grid.y: 0=A2h 1=A3h 2=B1h 3=B2h. Same MFMA structure as k_edge_fused phase 2.
__global__ __launch_bounds__(256) void k_tile_linear4(
    const float* __restrict__ x, int R,
    const float* __restrict__ w0, const float* __restrict__ b0, uint16_t* __restrict__ o0,
    const float* __restrict__ w1, const float* __restrict__ b1, uint16_t* __restrict__ o1,
    const float* __restrict__ w2, const float* __restrict__ b2, uint16_t* __restrict__ o2,
    const float* __restrict__ w3, const float* __restrict__ b3, uint16_t* __restrict__ o3)
{
    const float* w; const float* b; uint16_t* o;
    switch (blockIdx.y) {
        case 0:  w = w0; b = b0; o = o0; break;
        case 1:  w = w1; b = b1; o = o1; break;
        case 2:  w = w2; b = b2; o = o2; break;
        default: w = w3; b = b3; o = o3; break;
    }
    __shared__ __align__(16) uint16_t ldsEb[TILE * ESTR];  // bf16 x
    __shared__ __align__(16) uint16_t ldsBG[TILE * ESTR];  // bf16 W -> bf16 out
    uint32_t* eb32 = reinterpret_cast<uint32_t*>(ldsEb);
    int tid  = threadIdx.x;
    int lane = tid & 63;
    int base = blockIdx.x * TILE;
    int rem  = R - base; if (rem > TILE) rem = TILE;
    int qu   = __builtin_amdgcn_readfirstlane(tid >> 6);

    // stage x (bf16) and W (bf16)
    const float4* x4 = reinterpret_cast<const float4*>(x + (size_t)base * DD);
    #pragma unroll
    for (int j = 0; j < 4; ++j) {
        int f4 = j * 256 + tid;
        int r  = f4 >> 4, c = f4 & 15;
        if (r < rem) {
            float4 v = x4[f4];
            eb32[r * (ESTR / 2) + 2 * c + 0] = pack2(v.x, v.y);
            eb32[r * (ESTR / 2) + 2 * c + 1] = pack2(v.z, v.w);
        }
    }
    #pragma unroll
    for (int i = 0; i < 16; ++i) {
        int idx = i * 256 + tid;             // 0..4095 (W is L2-hot 16KB)
        int r = idx >> 6, c = idx & 63;
        ldsBG[r * ESTR + c] = (uint16_t)bf16r(w[idx]);
    }
    __syncthreads();

    // MFMA: out[16qu..16qu+16) x d[0..64) = x-slice @ W^T
    int kg   = lane >> 4;
    int lrow = lane & 15;
    f32x4 acc[4] = {{0,0,0,0},{0,0,0,0},{0,0,0,0},{0,0,0,0}};
    bf16x8 a0 = __builtin_bit_cast(bf16x8,
        *(const u32x4*)&ldsEb[(qu * 16 + lrow) * ESTR + kg * 8]);
    bf16x8 a1 = __builtin_bit_cast(bf16x8,
        *(const u32x4*)&ldsEb[(qu * 16 + lrow) * ESTR + 32 + kg * 8]);
    #pragma unroll
    for (int t = 0; t < 4; ++t) {
        bf16x8 bb0 = __builtin_bit_cast(bf16x8,
            *(const u32x4*)&ldsBG[(t * 16 + lrow) * ESTR + kg * 8]);
        bf16x8 bb1 = __builtin_bit_cast(bf16x8,
            *(const u32x4*)&ldsBG[(t * 16 + lrow) * ESTR + 32 + kg * 8]);
        acc[t] = __builtin_amdgcn_mfma_f32_16x16x32_bf16(a0, bb0, acc[t], 0, 0, 0);
        acc[t] = __builtin_amdgcn_mfma_f32_16x16x32_bf16(a1, bb1, acc[t], 0, 0, 0);
    }
    __syncthreads();   // W reads done -> reuse ldsBG for the output tile

    #pragma unroll
    for (int t = 0; t < 4; ++t) {
        float bias = b[t * 16 + lrow];
        #pragma unroll
        for (int r = 0; r < 4; ++r) {
            ldsBG[(qu * 16 + kg * 4 + r) * ESTR + t * 16 + lrow] =
                (uint16_t)bf16r(acc[t][r] + bias);
        }
    }
    __syncthreads();

    // coalesced bf16 writeout: uint2 = 4 bf16
    uint2* ob2 = reinterpret_cast<uint2*>(o);
    #pragma unroll
    for (int j = 0; j < 4; ++j) {
        int f = j * 256 + tid;       // [0,1024): 64 rows x 16 uint2
        int r = f >> 4, q = f & 15;
        if (r < rem)
            ob2[(size_t)(base + r) * 16 + q] = *(const uint2*)&ldsBG[r * ESTR + 4 * q];
    }
}

// =============== fused edge gate (MFMA, 64-edge tiles, tile-local place) =====
__global__ __launch_bounds__(256) void k_edge_fused(
    const float* __restrict__ e,
    const int* __restrict__ src, const int* __restrict__ dst,
    const uint16_t* __restrict__ B1b, const uint16_t* __restrict__ B2b,
    const float* __restrict__ w, const float* __restrict__ b,
    uint32_t* __restrict__ packed, float4* ecopy, float* __restrict__ sums,
    int* __restrict__ cur2, int2* __restrict__ pair2, int N, int E)
{
    __shared__ __align__(16) uint16_t ldsEb[TILE * ESTR];  // bf16 e   (9216 B)
    __shared__ __align__(16) uint16_t ldsBG[TILE * ESTR];  // bf16 B3 -> bf16 g0
    __shared__ float red[256];
    uint32_t* eb32 = reinterpret_cast<uint32_t*>(ldsEb);
    int tid  = threadIdx.x;
    int lane = tid & 63;
    int base = blockIdx.x * TILE;
    int rem  = E - base; if (rem > TILE) rem = TILE;
    int qu   = __builtin_amdgcn_readfirstlane(tid >> 6);

    // phase 0a: read e tile into regs
    const float4* e4 = reinterpret_cast<const float4*>(e + (size_t)base * DD);
    float4 ev[4];
    #pragma unroll
    for (int j = 0; j < 4; ++j) {
        int f4 = j * 256 + tid;
        int r  = f4 >> 4;
        ev[j] = (r < rem) ? e4[f4] : float4{0.f, 0.f, 0.f, 0.f};
    }

    // phase 0b: issue this wave's 32 bf16 B-row loads (latency hides under MFMA)
    float b1r[16], b2r[16];
    #pragma unroll
    for (int it = 0; it < 16; ++it) {
        int el = qu * 16 + it;               // wave-uniform
        if (el < rem) {
            int ee = base + el;
            int s = src[ee], t = dst[ee];    // scalar loads (uniform address)
            b1r[it] = bfl((uint32_t)B1b[(size_t)s * DD + lane]);
            b2r[it] = bfl((uint32_t)B2b[(size_t)t * DD + lane]);
        } else { b1r[it] = 0.f; b2r[it] = 0.f; }
    }

    // phase 0c: tile-local CSR place (threads 0..rem-1; src/dst L1-hot)
    if (tid < rem) {
        int ee = base + tid;
        int s = src[ee], t = dst[ee];
        int pf = atomicAdd(&cur2[t], 1);
        pair2[pf] = make_int2(ee, s);
        int pb = atomicAdd(&cur2[N + s], 1);
        pair2[pb] = make_int2(ee, t);        // bwd slots live at [E, 2E)
    }

    // phase 1: bf16 e -> ldsEb, bf16 B3 -> ldsBG, fp32 e passthrough
    #pragma unroll
    for (int j = 0; j < 4; ++j) {
        int f4 = j * 256 + tid;
        int r  = f4 >> 4, c = f4 & 15;
        if (r < rem) {
            eb32[r * (ESTR / 2) + 2 * c + 0] = pack2(ev[j].x, ev[j].y);
            eb32[r * (ESTR / 2) + 2 * c + 1] = pack2(ev[j].z, ev[j].w);
            if (ecopy) ecopy[(size_t)base * 16 + f4] = ev[j];
        }
    }
    #pragma unroll
    for (int i = 0; i < 16; ++i) {
        int idx = i * 256 + tid;             // 0..4095, coalesced (L2-hot 16KB)
        int r = idx >> 6, c = idx & 63;
        ldsBG[r * ESTR + c] = (uint16_t)bf16r(w[idx]);
    }
    __syncthreads();

    // phase 2: MFMA  g0[16qu..16qu+16) x d[0..64) = e-slice @ B3^T
    int kg   = lane >> 4;
    int lrow = lane & 15;
    f32x4 acc[4] = {{0,0,0,0},{0,0,0,0},{0,0,0,0},{0,0,0,0}};
    bf16x8 a0 = __builtin_bit_cast(bf16x8,
        *(const u32x4*)&ldsEb[(qu * 16 + lrow) * ESTR + kg * 8]);        // k 0..31
    bf16x8 a1 = __builtin_bit_cast(bf16x8,
        *(const u32x4*)&ldsEb[(qu * 16 + lrow) * ESTR + 32 + kg * 8]);   // k 32..63
    #pragma unroll
    for (int t = 0; t < 4; ++t) {
        bf16x8 bb0 = __builtin_bit_cast(bf16x8,
            *(const u32x4*)&ldsBG[(t * 16 + lrow) * ESTR + kg * 8]);
        bf16x8 bb1 = __builtin_bit_cast(bf16x8,
            *(const u32x4*)&ldsBG[(t * 16 + lrow) * ESTR + 32 + kg * 8]);
        acc[t] = __builtin_amdgcn_mfma_f32_16x16x32_bf16(a0, bb0, acc[t], 0, 0, 0);
        acc[t] = __builtin_amdgcn_mfma_f32_16x16x32_bf16(a1, bb1, acc[t], 0, 0, 0);
    }
    __syncthreads();   // all waves done reading B3 -> ldsBG reusable for g0

    // D store (m89-verified C/D map: col = lane&15, row = (lane>>4)*4 + reg)
    #pragma unroll
    for (int t = 0; t < 4; ++t) {
        float bias = b[t * 16 + lrow];
        #pragma unroll
        for (int r = 0; r < 4; ++r) {
            ldsBG[(qu * 16 + kg * 4 + r) * ESTR + t * 16 + lrow] =
                (uint16_t)bf16r(acc[t][r] + bias);
        }
    }
    __syncthreads();

    // phase 3: v = g0 + B1row + B2row, stats, packed bf16 (g,e) write
    float ps = 0.f, pq = 0.f;
    #pragma unroll
    for (int it = 0; it < 16; ++it) {
        int el = qu * 16 + it;
        if (el < rem) {
            int ee = base + el;
            uint32_t ebits = ldsEb[el * ESTR + lane];
            uint32_t gbits = ldsBG[el * ESTR + lane];
            float gv = __uint_as_float(gbits << 16);
            float v  = gv + b1r[it] + b2r[it];
            packed[(size_t)ee * DD + lane] = (ebits << 16) | bf16r(v);
            ps += v; pq += v * v;
        }
    }
    float* srep = sums + (size_t)(blockIdx.x & (NREP - 1)) * 128;
    red[tid] = ps; __syncthreads();
    if (tid < 64) fatomic_add(&srep[tid],      red[tid] + red[tid+64] + red[tid+128] + red[tid+192]);
    __syncthreads();
    red[tid] = pq; __syncthreads();
    if (tid < 64) fatomic_add(&srep[64 + tid], red[tid] + red[tid+64] + red[tid+128] + red[tid+192]);
}

// ---------------- fold replicated stats into scale/shift ---------------------
__global__ void k_bn_final(const float* __restrict__ reps, float inv_cnt,
                           const float* __restrict__ gamma, const float* __restrict__ beta,
                           float* __restrict__ scale, float* __restrict__ shift)
{
    int d = threadIdx.x;
    if (d >= DD) return;
    float s = 0.f, q = 0.f;
    #pragma unroll 8
    for (int r = 0; r < NREP; ++r) {
        s += reps[r * 128 + d];
        q += reps[r * 128 + 64 + d];
    }
    float mean = s * inv_cnt;
    float var  = fmaxf(q * inv_cnt - mean * mean, 0.f);
    float rs   = rsqrtf(var + BN_EPS);
    float sc   = gamma[d] * rs;
    scale[d] = sc;
    shift[d] = beta[d] - mean * sc;
}

// hierarchical exclusive scan: block-local -> add (carry computed inline)
__global__ __launch_bounds__(1024) void k_scan_blk(
    const int* __restrict__ cnt, int* __restrict__ row, int* __restrict__ part, int n)
{
    __shared__ int tmp[1024];
    int tid = threadIdx.x;
    int i   = blockIdx.x * 1024 + tid;
    int v   = (i < n) ? cnt[i] : 0;
    tmp[tid] = v; __syncthreads();
    for (int off = 1; off < 1024; off <<= 1) {
        int t = (tid >= off) ? tmp[tid - off] : 0;
        __syncthreads();
        tmp[tid] += t;
        __syncthreads();
    }
    if (i < n) row[i] = tmp[tid] - v;            // local exclusive
    if (tid == 1023) part[blockIdx.x] = tmp[1023];  // raw block total
}

__global__ __launch_bounds__(1024) void k_scan_add(
    int* __restrict__ row, int* __restrict__ cur, const int* __restrict__ part,
    int n, int total)
{
    int carry = 0;
    for (int j = 0; j < (int)blockIdx.x; ++j) carry += part[j];  // uniform s_loads
    int i = blockIdx.x * 1024 + threadIdx.x;
    if (i < n) {
        int r = row[i] + carry;
        row[i] = r; cur[i] = r;
    }
    if (i == 0) row[n] = total;
}

// ---------------- merged gather, 16 edges in flight, bf16 Ah -----------------
__global__ __launch_bounds__(256) void k_gather2(
    const uint32_t* __restrict__ packed,
    const int2* __restrict__ pair2, const int* __restrict__ row2,
    const uint16_t* __restrict__ A2b, const uint16_t* __restrict__ A3b,
    const float* __restrict__ e_scale, const float* __restrict__ e_shift,
    float* __restrict__ agg_f, float* __restrict__ agg_b, int N)
{
    int gw = (blockIdx.x * 256 + threadIdx.x) >> 6;
    if (gw >= 2 * N) return;
    int lane = threadIdx.x & 63;
    bool bwd = gw >= N;
    int wid  = bwd ? gw - N : gw;
    const uint2* Ah2 = reinterpret_cast<const uint2*>(bwd ? A3b : A2b);
    float* agg       = bwd ? agg_b : agg_f;
    int beg = row2[gw], end = row2[gw + 1];   // fwd rows [0,N), bwd rows [N,2N)
    int q  = lane >> 4;      // edge slot 0..3
    int dj = lane & 15;      // float4 column slot
    float4 sc = reinterpret_cast<const float4*>(e_scale)[dj];
    float4 sh = reinterpret_cast<const float4*>(e_shift)[dj];
    float4 num = {0.f, 0.f, 0.f, 0.f};
    float4 den = {0.f, 0.f, 0.f, 0.f};
    const uint4* p4 = reinterpret_cast<const uint4*>(packed);
    for (int k = beg + q; k < end; k += 16) {
        bool h1 = k + 4 < end, h2 = k + 8 < end, h3 = k + 12 < end;
        int2 p0 = pair2[k];
        int2 p1 = h1 ? pair2[k + 4]  : p0;
        int2 p2 = h2 ? pair2[k + 8]  : p0;
        int2 p3 = h3 ? pair2[k + 12] : p0;
        uint4 w0 = p4[(size_t)p0.x * 16 + dj];
        uint4 w1 = p4[(size_t)p1.x * 16 + dj];
        uint4 w2 = p4[(size_t)p2.x * 16 + dj];
        uint4 w3 = p4[(size_t)p3.x * 16 + dj];
        uint2 a0 = Ah2[(size_t)p0.y * 16 + dj];
        uint2 a1 = Ah2[(size_t)p1.y * 16 + dj];
        uint2 a2 = Ah2[(size_t)p2.y * 16 + dj];
        uint2 a3 = Ah2[(size_t)p3.y * 16 + dj];
        float m1 = h1 ? 1.f : 0.f, m2 = h2 ? 1.f : 0.f, m3 = h3 ? 1.f : 0.f;
        #define ACC_PAIR(wv, av, m)                                              \
        {                                                                        \
            float s0 = 1.f / (1.f + __expf(-(fmaxf(bfl(wv.x) * sc.x + sh.x, 0.f) + bfh(wv.x)))); \
            float s1 = 1.f / (1.f + __expf(-(fmaxf(bfl(wv.y) * sc.y + sh.y, 0.f) + bfh(wv.y)))); \
            float s2 = 1.f / (1.f + __expf(-(fmaxf(bfl(wv.z) * sc.z + sh.z, 0.f) + bfh(wv.z)))); \
            float s3 = 1.f / (1.f + __expf(-(fmaxf(bfl(wv.w) * sc.w + sh.w, 0.f) + bfh(wv.w)))); \
            s0 *= m; s1 *= m; s2 *= m; s3 *= m;                                  \
            num.x = fmaf(s0, bfl(av.x), num.x);                                  \
            num.y = fmaf(s1, bfh(av.x), num.y);                                  \
            num.z = fmaf(s2, bfl(av.y), num.z);                                  \
            num.w = fmaf(s3, bfh(av.y), num.w);                                  \
            den.x += s0; den.y += s1; den.z += s2; den.w += s3;                  \
        }
        ACC_PAIR(w0, a0, 1.f)
        ACC_PAIR(w1, a1, m1)
        ACC_PAIR(w2, a2, m2)
        ACC_PAIR(w3, a3, m3)
        #undef ACC_PAIR
    }
    #pragma unroll
    for (int off = 16; off <= 32; off <<= 1) {
        num.x += __shfl_xor(num.x, off); num.y += __shfl_xor(num.y, off);
        num.z += __shfl_xor(num.z, off); num.w += __shfl_xor(num.w, off);
        den.x += __shfl_xor(den.x, off); den.y += __shfl_xor(den.y, off);
        den.z += __shfl_xor(den.z, off); den.w += __shfl_xor(den.w, off);
    }
    if (q == 0) {
        float4 res;
        res.x = num.x / (den.x + DEG_EPS);
        res.y = num.y / (den.y + DEG_EPS);
        res.z = num.z / (den.z + DEG_EPS);
        res.w = num.w / (den.w + DEG_EPS);
        reinterpret_cast<float4*>(agg)[(size_t)wid * 16 + dj] = res;
    }
}

// ---------------- h_pre = A1h + agg_f + agg_b, + replicated column stats -----
__global__ __launch_bounds__(256) void k_node_pre(
    const float* __restrict__ A1h,
    const float* __restrict__ agg_f, const float* __restrict__ agg_b,
    float* __restrict__ hpre, float* __restrict__ sums, long long total)
{
    int tid = threadIdx.x;
    long long idx = (long long)blockIdx.x * 256 + tid;
    long long stride = (long long)gridDim.x * 256;
    float ps = 0.f, pq = 0.f;
    for (; idx < total; idx += stride) {
        float v = A1h[idx] + agg_f[idx] + agg_b[idx];
        hpre[idx] = v;
        ps += v; pq += v * v;
    }
    float* srep = sums + (size_t)(blockIdx.x & (NREP - 1)) * 128;
    __shared__ float red[256];
    red[tid] = ps; __syncthreads();
    if (tid < 64) fatomic_add(&srep[tid],      red[tid] + red[tid+64] + red[tid+128] + red[tid+192]);
    __syncthreads();
    red[tid] = pq; __syncthreads();
    if (tid < 64) fatomic_add(&srep[64 + tid], red[tid] + red[tid+64] + red[tid+128] + red[tid+192]);
}

// ---------------- finish h: BN affine + relu + residual (in place) -----------
__global__ __launch_bounds__(256) void k_node_out(
    const float* __restrict__ h,
    const float* __restrict__ scale, const float* __restrict__ shift,
    float* __restrict__ out, long long total)
{
    long long idx = (long long)blockIdx.x * 256 + threadIdx.x;
    long long stride = (long long)gridDim.x * 256;
    for (; idx < total; idx += stride) {
        int d = (int)(idx & (DD - 1));
        float v = out[idx] * scale[d] + shift[d];
        out[idx] = fmaxf(v, 0.f) + h[idx];
    }
}

extern "C" void kernel_launch(void* const* d_in, const int* in_sizes, int n_in,
                              void* d_out, int out_size, void* d_ws, size_t ws_size,
                              hipStream_t stream)
{
    const float* h    = (const float*)d_in[0];
    const float* e    = (const float*)d_in[1];
    const int*   src  = (const int*)d_in[2];
    const int*   dst  = (const int*)d_in[3];
    const float* A1w  = (const float*)d_in[4];
    const float* A1b  = (const float*)d_in[5];
    const float* A2w  = (const float*)d_in[6];
    const float* A2b  = (const float*)d_in[7];
    const float* A3w  = (const float*)d_in[8];
    const float* A3b  = (const float*)d_in[9];
    const float* B1w  = (const float*)d_in[10];
    const float* B1b  = (const float*)d_in[11];
    const float* B2w  = (const float*)d_in[12];
    const float* B2b  = (const float*)d_in[13];
    const float* B3w  = (const float*)d_in[14];
    const float* B3b  = (const float*)d_in[15];
    const float* bnhg = (const float*)d_in[16];
    const float* bnhb = (const float*)d_in[17];
    const float* bneg = (const float*)d_in[18];
    const float* bneb = (const float*)d_in[19];

    const int N = in_sizes[0] / DD;
    const int E = in_sizes[1] / DD;
    const size_t ND = (size_t)N * DD;
    const size_t ED = (size_t)E * DD;

    float* ws    = (float*)d_ws;
    float* A1h   = ws + 0 * ND;
    float* A2h   = ws + 1 * ND;   // bf16 content
    float* A3h   = ws + 2 * ND;   // bf16 content
    float* B1h   = ws + 3 * ND;   // bf16 content
    float* B2h   = ws + 4 * ND;   // bf16 content
    float* agg_f = ws + 5 * ND;
    float* agg_b = ws + 6 * ND;
    float* stats = ws + 7 * ND;
    const size_t STATS_F = 16640;
    float* e_rep   = stats;
    float* h_rep   = stats + 8192;
    float* e_scale = stats + 16384;
    float* e_shift = stats + 16448;
    float* h_scale = stats + 16512;
    float* h_shift = stats + 16576;

    const int nscan   = 2 * N;
    const int nb_scan = (nscan + 1023) / 1024;

    // ints directly after stats -> stats+cur2 zeroed in ONE memset
    int*  ibase  = (int*)(stats + STATS_F);
    int*  cur2   = ibase;                     // 2N (counts -> cursors)
    int*  row2   = ibase + 2 * N;             // 2N+1
    int*  part   = ibase + 4 * N + 1;         // nb_scan (raw block sums)
    int2* pair2  = (int2*)(((uintptr_t)(part + nb_scan) + 7) & ~(uintptr_t)7); // 2E pairs
    uint32_t* pk_ws = (uint32_t*)(pair2 + 2 * (size_t)E);  // ED u32 (if ws_big)

    const size_t need_big = (size_t)((char*)(pk_ws + ED) - (char*)d_ws);
    const bool   ws_big   = ws_size >= need_big;

    float* out  = (float*)d_out;
    float* gbuf = out + ND;   // out e-region

    hipMemsetAsync(stats, 0, STATS_F * sizeof(float) + 2 * (size_t)N * sizeof(int), stream);

    dim3 blk(256);
    int nt_n  = (N + TILE - 1) / TILE;
    int nt_e  = (E + TILE - 1) / TILE;

    // node linears: A1 (fp32 + degree count) and the 4 bf16 tables (MFMA)
    k_tile_linear1<<<nt_n, blk, 0, stream>>>(h, N, A1w, A1b, A1h,
                                             src, dst, cur2, N, E);
    k_tile_linear4<<<dim3(nt_n, 4), blk, 0, stream>>>(h, N,
        A2w, A2b, (uint16_t*)A2h,  A3w, A3b, (uint16_t*)A3h,
        B1w, B1b, (uint16_t*)B1h,  B2w, B2b, (uint16_t*)B2h);

    // CSR scan (carry folded into scan_add); place fused into edge_fused
    k_scan_blk<<<nb_scan, 1024, 0, stream>>>(cur2, row2, part, nscan);
    k_scan_add<<<nb_scan, 1024, 0, stream>>>(row2, cur2, part, nscan, 2 * E);

    // fused edge gate + BN-e stats + packed (g,e) + e passthrough + tile place
    uint32_t* pkmem = ws_big ? pk_ws : (uint32_t*)gbuf;
    k_edge_fused<<<nt_e, blk, 0, stream>>>(e, src, dst,
                                           (const uint16_t*)B1h, (const uint16_t*)B2h,
                                           B3w, B3b,
                                           pkmem, ws_big ? (float4*)gbuf : nullptr,
                                           e_rep, cur2, pair2, N, E);
    k_bn_final<<<1, 64, 0, stream>>>(e_rep, 1.0f / (float)E, bneg, bneb,
                                     e_scale, e_shift);

    // merged gather with inline sigma recompute from packed rows
    int nb_g2 = (int)(((size_t)2 * N * 64 + 255) / 256);
    k_gather2<<<nb_g2, blk, 0, stream>>>(pkmem, pair2, row2,
                                         (const uint16_t*)A2h, (const uint16_t*)A3h,
                                         e_scale, e_shift, agg_f, agg_b, N);

    k_node_pre<<<1024, blk, 0, stream>>>(A1h, agg_f, agg_b,
        out, h_rep, (long long)ND);
    k_bn_final<<<1, 64, 0, stream>>>(h_rep, 1.0f / (float)N, bnhg, bnhb,
                                     h_scale, h_shift);
    k_node_out<<<1024, blk, 0, stream>>>(h, h_scale, h_shift,
                                         out, (long long)ND);

    if (!ws_big) {
        hipMemcpyAsync(gbuf, e, ED * sizeof(float), hipMemcpyDeviceToDevice, stream);
    }
}